// Round 11
// baseline (4237.183 us; speedup 1.0000x reference)
//
#include <hip/hip_runtime.h>

#define NUM_USERS 50000
#define NUM_ITEMS 50000
#define N_NODES   100000
#define NNZ       3200000
#define EMB_DIM   64
#define N_LAYERS  3
#define BATCH     16384

#define NBUCK 512
#define ABITS 8                  // bucket = dst >> 8 (256 nodes/bucket, 391 used)
#define NODES_PER_BUCK 256
#define TILE_EDGES 8192
#define NBUCK_USED ((N_NODES + NODES_PER_BUCK - 1) / NODES_PER_BUCK)   // 391
#define CAP 9216                 // padded bucket capacity (mean 8192, +11 sigma)
#define LSTRIDE 65               // LDS floats per node (64 + 1 pad -> bank spread)

typedef unsigned long long ull;

// ---- bf16 helpers ----
__device__ inline unsigned bf16pair(float a, float b) {
    unsigned ua = __float_as_uint(a), ub = __float_as_uint(b);
    unsigned r0 = (ua + 0x7fffu + ((ua >> 16) & 1u)) >> 16;
    unsigned r1 = (ub + 0x7fffu + ((ub >> 16) & 1u)) >> 16;
    return r0 | (r1 << 16);
}
__device__ inline float blo(unsigned u) { return __uint_as_float(u << 16); }
__device__ inline float bhi(unsigned u) { return __uint_as_float(u & 0xffff0000u); }

// init: acc(fp32) = concat(ue, ie); bufA16(bf16) = same.
// Block 0 inits ALL 512 bucket cursors to their padded region base (ws is poisoned).
__global__ void init_emb_kernel(const float* __restrict__ ue,
                                const float* __restrict__ ie,
                                unsigned* __restrict__ bufA16,
                                float* __restrict__ acc,
                                int* __restrict__ bucketCursor) {
    int idx = blockIdx.x * blockDim.x + threadIdx.x;   // per float4 (4 dims)
    if (blockIdx.x == 0 && threadIdx.x < 256) {
        bucketCursor[threadIdx.x]       = threadIdx.x * CAP;
        bucketCursor[threadIdx.x + 256] = (threadIdx.x + 256) * CAP;
    }
    const int total = N_NODES * (EMB_DIM / 4);
    if (idx >= total) return;
    const int uoff = NUM_USERS * (EMB_DIM / 4);
    float4 v;
    if (idx < uoff) v = ((const float4*)ue)[idx];
    else            v = ((const float4*)ie)[idx - uoff];
    ((float4*)acc)[idx] = v;
    uint2 h;
    h.x = bf16pair(v.x, v.y);
    h.y = bf16pair(v.z, v.w);
    ((uint2*)bufA16)[idx] = h;
}

// partition edges into padded dst-bucket regions. 1024 threads, 8 edges/thread.
// rec: src(17) | dstLocal(8)<<17 | fix15(val)<<25
__global__ void partA_kernel(const float* __restrict__ ev,
                             const int*  __restrict__ es,
                             const int*  __restrict__ ed,
                             int* __restrict__ bucketCursor,
                             ull* __restrict__ tmp) {
    __shared__ int hist[NBUCK];
    __shared__ int base[NBUCK];
    __shared__ int cnt2[NBUCK];
    int tid = threadIdx.x;            // 1024
    int e0 = blockIdx.x * TILE_EDGES;

    int      mySrc[8], myDst[8];
    unsigned myQ[8];

    for (int i = tid; i < NBUCK; i += 1024) hist[i] = 0;
    __syncthreads();

    #pragma unroll
    for (int k = 0; k < 8; ++k) {
        int e = e0 + k * 1024 + tid;
        if (e < NNZ) {
            mySrc[k] = es[e];
            myDst[k] = ed[e];
            myQ[k]   = (unsigned)fminf(ev[e] * 32768.f + 0.5f, 32767.f);
            atomicAdd(&hist[((unsigned)myDst[k]) >> ABITS], 1);
        } else {
            myDst[k] = -1;
        }
    }
    __syncthreads();

    for (int i = tid; i < NBUCK; i += 1024) {
        int c = hist[i];
        base[i] = c ? atomicAdd(&bucketCursor[i], c) : 0;
        cnt2[i] = 0;
    }
    __syncthreads();

    #pragma unroll
    for (int k = 0; k < 8; ++k) {
        int dst = myDst[k];
        if (dst < 0) continue;
        int b = ((unsigned)dst) >> ABITS;
        int pos = base[b] + atomicAdd(&cnt2[b], 1);
        if (pos < (b + 1) * CAP) {   // statistically unreachable guard
            ull rec = (ull)(unsigned)(mySrc[k] | ((dst & (NODES_PER_BUCK - 1)) << 17))
                    | ((ull)myQ[k] << 25);
            tmp[pos] = rec;
        }
    }
}

// ---- pull: one block per dst bucket; LDS fp32 accumulator tile (256 x 64, stride 65).
// 8 lanes per edge (d8 = dim octet), 128 edge-groups/block, unroll-2.
__global__ __launch_bounds__(1024) void pull_kernel(const uint4* __restrict__ A16,
                                                    unsigned* __restrict__ B16,
                                                    float* __restrict__ acc,
                                                    const ull* __restrict__ tmp,
                                                    const int* __restrict__ bucketCursor,
                                                    int writeB) {
    __shared__ float accL[NODES_PER_BUCK * LSTRIDE];   // 66,560 B
    int b   = blockIdx.x;
    int tid = threadIdx.x;
    int nodeLo = b << ABITS;
    int base   = b * CAP;
    int cnt    = bucketCursor[b] - base;   // edges in this bucket

    for (int i = tid; i < NODES_PER_BUCK * LSTRIDE; i += 1024) accL[i] = 0.f;
    __syncthreads();

    const ull* ep = tmp + base;
    int g  = tid >> 3;       // 0..127 edge group
    int d8 = tid & 7;        // dim octet
    const float k15 = 1.f / 32768.f;

    for (int i = g; i < cnt; i += 256) {
        ull r0 = ep[i];
        int i2 = i + 128;
        ull r1 = (i2 < cnt) ? ep[i2] : 0ULL;    // rec 0 -> w=0, harmless
        int   s0  = (int)(r0 & 0x1FFFFULL);
        int   dl0 = (int)((r0 >> 17) & 0xFF);
        float w0  = (float)((unsigned)((r0 >> 25) & 0x7FFF)) * k15;
        int   s1  = (int)(r1 & 0x1FFFFULL);
        int   dl1 = (int)((r1 >> 17) & 0xFF);
        float w1  = (float)((unsigned)((r1 >> 25) & 0x7FFF)) * k15;
        uint4 g0 = A16[((long long)s0 << 3) + d8];
        uint4 g1 = A16[((long long)s1 << 3) + d8];
        float* p0 = accL + dl0 * LSTRIDE + d8 * 8;
        atomicAdd(p0 + 0, w0 * blo(g0.x)); atomicAdd(p0 + 1, w0 * bhi(g0.x));
        atomicAdd(p0 + 2, w0 * blo(g0.y)); atomicAdd(p0 + 3, w0 * bhi(g0.y));
        atomicAdd(p0 + 4, w0 * blo(g0.z)); atomicAdd(p0 + 5, w0 * bhi(g0.z));
        atomicAdd(p0 + 6, w0 * blo(g0.w)); atomicAdd(p0 + 7, w0 * bhi(g0.w));
        float* p1 = accL + dl1 * LSTRIDE + d8 * 8;
        atomicAdd(p1 + 0, w1 * blo(g1.x)); atomicAdd(p1 + 1, w1 * bhi(g1.x));
        atomicAdd(p1 + 2, w1 * blo(g1.y)); atomicAdd(p1 + 3, w1 * bhi(g1.y));
        atomicAdd(p1 + 4, w1 * blo(g1.z)); atomicAdd(p1 + 5, w1 * bhi(g1.z));
        atomicAdd(p1 + 6, w1 * blo(g1.w)); atomicAdd(p1 + 7, w1 * bhi(g1.w));
    }
    __syncthreads();

    // epilogue: acc += tile; B16 = bf16(tile)
    int nMax = N_NODES - nodeLo;
    if (nMax > NODES_PER_BUCK) nMax = NODES_PER_BUCK;
    float2* C2 = (float2*)acc;
    for (int idx = tid; idx < nMax * 32; idx += 1024) {
        int node = idx >> 5;
        int pr   = idx & 31;          // dim pair
        float v0 = accL[node * LSTRIDE + pr * 2];
        float v1 = accL[node * LSTRIDE + pr * 2 + 1];
        long long go = ((long long)(nodeLo + node) << 5) + pr;   // float2 index
        float2 c = C2[go];
        c.x += v0; c.y += v1;
        C2[go] = c;
        if (writeB) B16[go] = bf16pair(v0, v1);
    }
}

// one wave per batch element: dot(acc[u], acc[NUM_USERS+i]) / 16
__global__ void dot_kernel(const float* __restrict__ acc,
                           const int* __restrict__ users,
                           const int* __restrict__ items,
                           float* __restrict__ out) {
    int t = blockIdx.x * blockDim.x + threadIdx.x;
    int b = t >> 6;
    int d = t & 63;
    if (b >= BATCH) return;
    int u  = users[b];
    int it = items[b] + NUM_USERS;
    float p = acc[(long long)u * EMB_DIM + d] * acc[(long long)it * EMB_DIM + d];
    #pragma unroll
    for (int off = 32; off >= 1; off >>= 1)
        p += __shfl_down(p, off, 64);
    if (d == 0) out[b] = p * 0.0625f;
}

extern "C" void kernel_launch(void* const* d_in, const int* in_sizes, int n_in,
                              void* d_out, int out_size, void* d_ws, size_t ws_size,
                              hipStream_t stream) {
    const float* user_emb = (const float*)d_in[0];
    const float* item_emb = (const float*)d_in[1];
    const float* edge_val = (const float*)d_in[2];
    const int*   edge_src = (const int*)d_in[3];
    const int*   edge_dst = (const int*)d_in[4];
    const int*   users    = (const int*)d_in[5];
    const int*   items    = (const int*)d_in[6];
    float* out = (float*)d_out;

    const size_t emb16Bytes = (size_t)N_NODES * EMB_DIM * 2;             // 12.8 MB
    const size_t embBytes   = (size_t)N_NODES * EMB_DIM * sizeof(float); // 25.6 MB
    const size_t tmpBytes   = (size_t)NBUCK_USED * CAP * sizeof(ull);    // 28.8 MB

    char* w = (char*)d_ws;
    unsigned* bufA16       = (unsigned*)(w); w += emb16Bytes;
    unsigned* bufB16       = (unsigned*)(w); w += emb16Bytes;
    float*    acc          = (float*)(w);    w += embBytes;
    ull*      tmp          = (ull*)(w);      w += tmpBytes;
    int*      bucketCursor = (int*)(w);      w += NBUCK * sizeof(int);

    const int vecTotal   = N_NODES * (EMB_DIM / 4);
    const int initBlocks = (vecTotal + 255) / 256;
    const int tileBlocks = (NNZ + TILE_EDGES - 1) / TILE_EDGES;   // 391

    init_emb_kernel<<<initBlocks, 256, 0, stream>>>(user_emb, item_emb,
                                                    bufA16, acc, bucketCursor);

    partA_kernel<<<tileBlocks, 1024, 0, stream>>>(edge_val, edge_src, edge_dst,
                                                  bucketCursor, tmp);

    for (int layer = 0; layer < N_LAYERS; ++layer) {
        pull_kernel<<<NBUCK_USED, 1024, 0, stream>>>((const uint4*)bufA16, bufB16, acc,
                                                     tmp, bucketCursor,
                                                     layer < N_LAYERS - 1 ? 1 : 0);
        unsigned* tswap = bufA16; bufA16 = bufB16; bufB16 = tswap;
    }

    const int dotBlocks = (BATCH * 64 + 255) / 256;
    dot_kernel<<<dotBlocks, 256, 0, stream>>>(acc, users, items, out);
}

// Round 12
// 334.771 us; speedup vs baseline: 12.6570x; 12.6570x over previous
//
#include <hip/hip_runtime.h>

#define NUM_USERS 50000
#define NUM_ITEMS 50000
#define N_NODES   100000
#define NNZ       3200000
#define EMB_DIM   64
#define N_LAYERS  3
#define BATCH     16384

#define NBUCK 512
#define ABITS 8                  // bucket = dst >> 8 (256 nodes/bucket, 391 used)
#define NODES_PER_BUCK 256
#define TILE_EDGES 8192
#define NBUCK_USED ((N_NODES + NODES_PER_BUCK - 1) / NODES_PER_BUCK)   // 391
#define CAP 9216                 // padded bucket capacity (mean 8192, +11 sigma)

typedef unsigned long long ull;

// ---- bf16 helpers (RNE) ----
__device__ inline unsigned bf16pair(float a, float b) {
    unsigned ua = __float_as_uint(a), ub = __float_as_uint(b);
    unsigned r0 = (ua + 0x7fffu + ((ua >> 16) & 1u)) >> 16;
    unsigned r1 = (ub + 0x7fffu + ((ub >> 16) & 1u)) >> 16;
    return r0 | (r1 << 16);
}

// accumulate 8 bf16 dims (one uint4) * w into s[0..7]
__device__ inline void acc8(float* s, uint4 g, float w) {
    s[0] = fmaf(w, __uint_as_float(g.x << 16),        s[0]);
    s[1] = fmaf(w, __uint_as_float(g.x & 0xffff0000u), s[1]);
    s[2] = fmaf(w, __uint_as_float(g.y << 16),        s[2]);
    s[3] = fmaf(w, __uint_as_float(g.y & 0xffff0000u), s[3]);
    s[4] = fmaf(w, __uint_as_float(g.z << 16),        s[4]);
    s[5] = fmaf(w, __uint_as_float(g.z & 0xffff0000u), s[5]);
    s[6] = fmaf(w, __uint_as_float(g.w << 16),        s[6]);
    s[7] = fmaf(w, __uint_as_float(g.w & 0xffff0000u), s[7]);
}

// init: acc(fp32) = concat(ue, ie); bufA16(bf16) = same.
// Block 0 inits ALL 512 bucket cursors to their padded region base (ws is 0xAA-poisoned).
__global__ void init_emb_kernel(const float* __restrict__ ue,
                                const float* __restrict__ ie,
                                unsigned* __restrict__ bufA16,
                                float* __restrict__ acc,
                                int* __restrict__ bucketCursor) {
    int idx = blockIdx.x * blockDim.x + threadIdx.x;   // per float4 (4 dims)
    if (blockIdx.x == 0 && threadIdx.x < 256) {
        bucketCursor[threadIdx.x]       = threadIdx.x * CAP;
        bucketCursor[threadIdx.x + 256] = (threadIdx.x + 256) * CAP;
    }
    const int total = N_NODES * (EMB_DIM / 4);
    if (idx >= total) return;
    const int uoff = NUM_USERS * (EMB_DIM / 4);
    float4 v;
    if (idx < uoff) v = ((const float4*)ue)[idx];
    else            v = ((const float4*)ie)[idx - uoff];
    ((float4*)acc)[idx] = v;
    uint2 h;
    h.x = bf16pair(v.x, v.y);
    h.y = bf16pair(v.z, v.w);
    ((uint2*)bufA16)[idx] = h;
}

// partition edges into padded dst-bucket regions. 1024 threads, 8 edges/thread.
// rec: src(17) | dstLocal(8)<<17 | fix15(val)<<25
__global__ void partA_kernel(const float* __restrict__ ev,
                             const int*  __restrict__ es,
                             const int*  __restrict__ ed,
                             int* __restrict__ bucketCursor,
                             ull* __restrict__ tmp) {
    __shared__ int hist[NBUCK];
    __shared__ int base[NBUCK];
    __shared__ int cnt2[NBUCK];
    int tid = threadIdx.x;            // 1024
    int e0 = blockIdx.x * TILE_EDGES;

    int      mySrc[8], myDst[8];
    unsigned myQ[8];

    for (int i = tid; i < NBUCK; i += 1024) hist[i] = 0;
    __syncthreads();

    #pragma unroll
    for (int k = 0; k < 8; ++k) {
        int e = e0 + k * 1024 + tid;
        if (e < NNZ) {
            mySrc[k] = es[e];
            myDst[k] = ed[e];
            myQ[k]   = (unsigned)fminf(ev[e] * 32768.f + 0.5f, 32767.f);
            atomicAdd(&hist[((unsigned)myDst[k]) >> ABITS], 1);
        } else {
            myDst[k] = -1;
        }
    }
    __syncthreads();

    for (int i = tid; i < NBUCK; i += 1024) {
        int c = hist[i];
        base[i] = c ? atomicAdd(&bucketCursor[i], c) : 0;
        cnt2[i] = 0;
    }
    __syncthreads();

    #pragma unroll
    for (int k = 0; k < 8; ++k) {
        int dst = myDst[k];
        if (dst < 0) continue;
        int b = ((unsigned)dst) >> ABITS;
        int pos = base[b] + atomicAdd(&cnt2[b], 1);
        if (pos < (b + 1) * CAP) {   // statistically unreachable overflow guard
            ull rec = (ull)(unsigned)(mySrc[k] | ((dst & (NODES_PER_BUCK - 1)) << 17))
                    | ((ull)myQ[k] << 25);
            tmp[pos] = rec;
        }
    }
}

// partB: per bucket — count from cursor, node degrees + rowStart via LDS scan,
// scatter to padded-CSR positions. sorted rec (u32): src(17) | fix15(val)<<17
__global__ void partB_kernel(const ull* __restrict__ tmp,
                             const int* __restrict__ bucketCursor,
                             int* __restrict__ rowStart,
                             int* __restrict__ deg,
                             unsigned* __restrict__ sorted) {
    __shared__ int cnt[NODES_PER_BUCK];
    __shared__ int sc[NODES_PER_BUCK];
    __shared__ int cur[NODES_PER_BUCK];
    int b = blockIdx.x;
    int tid = threadIdx.x;           // 1024
    int nodeLo = b << ABITS;
    int startE = b * CAP;
    int endE   = bucketCursor[b];    // base + edges in bucket

    if (tid < NODES_PER_BUCK) cnt[tid] = 0;
    __syncthreads();
    for (int i = startE + tid; i < endE; i += 1024) {
        ull rec = tmp[i];
        atomicAdd(&cnt[(int)((rec >> 17) & (NODES_PER_BUCK - 1))], 1);
    }
    __syncthreads();
    if (tid < NODES_PER_BUCK) sc[tid] = cnt[tid];
    __syncthreads();
    for (int o = 1; o < NODES_PER_BUCK; o <<= 1) {
        int add = 0;
        if (tid < NODES_PER_BUCK && tid >= o) add = sc[tid - o];
        __syncthreads();
        if (tid < NODES_PER_BUCK) sc[tid] += add;
        __syncthreads();
    }
    if (tid < NODES_PER_BUCK) {
        int node = nodeLo + tid;
        int rs = startE + sc[tid] - cnt[tid];
        cur[tid] = rs;
        if (node < N_NODES) {
            rowStart[node] = rs;          // index into padded sorted array
            deg[node] = cnt[tid];
        }
    }
    __syncthreads();
    for (int i = startE + tid; i < endE; i += 1024) {
        ull rec = tmp[i];
        int dl = (int)((rec >> 17) & (NODES_PER_BUCK - 1));
        unsigned o = (unsigned)(rec & 0x1FFFFULL) | ((unsigned)((rec >> 25) & 0x7FFF) << 17);
        int pos = atomicAdd(&cur[dl], 1);
        sorted[pos] = o;
    }
}

// ---- pull: one wave per dst node; lane = (eg=lane>>3 edge subgroup, d8=lane&7 dim octet).
// u32 edge records; uint4 bf16 gathers; 32 edges in flight (4 batches of 8).
__global__ void pull_kernel(const uint4* __restrict__ A16,
                            uint4* __restrict__ B16,
                            float* __restrict__ acc,
                            const unsigned* __restrict__ sorted,
                            const int* __restrict__ rowStart,
                            const int* __restrict__ deg,
                            int writeB) {
    int t = blockIdx.x * blockDim.x + threadIdx.x;
    int node = t >> 6;
    if (node >= N_NODES) return;
    int lane = t & 63;
    int eg = lane >> 3;      // 0..7
    int d8 = lane & 7;       // dim octet (16 B)
    int start = rowStart[node];
    int cnt   = deg[node];   // wave-uniform
    const unsigned* ep = sorted + start;
    const float k15 = 1.f / 32768.f;

    float s[8] = {0.f,0.f,0.f,0.f,0.f,0.f,0.f,0.f};
    int j = 0;
    while (j + 32 <= cnt) {
        unsigned r0 = ep[j + eg], r1 = ep[j + 8 + eg];
        unsigned r2 = ep[j + 16 + eg], r3 = ep[j + 24 + eg];
        uint4 g0 = A16[(((long long)(r0 & 0x1FFFFu)) << 3) + d8];
        uint4 g1 = A16[(((long long)(r1 & 0x1FFFFu)) << 3) + d8];
        uint4 g2 = A16[(((long long)(r2 & 0x1FFFFu)) << 3) + d8];
        uint4 g3 = A16[(((long long)(r3 & 0x1FFFFu)) << 3) + d8];
        acc8(s, g0, (float)(r0 >> 17) * k15);
        acc8(s, g1, (float)(r1 >> 17) * k15);
        acc8(s, g2, (float)(r2 >> 17) * k15);
        acc8(s, g3, (float)(r3 >> 17) * k15);
        j += 32;
    }
    while (j + 16 <= cnt) {
        unsigned r0 = ep[j + eg], r1 = ep[j + 8 + eg];
        uint4 g0 = A16[(((long long)(r0 & 0x1FFFFu)) << 3) + d8];
        uint4 g1 = A16[(((long long)(r1 & 0x1FFFFu)) << 3) + d8];
        acc8(s, g0, (float)(r0 >> 17) * k15);
        acc8(s, g1, (float)(r1 >> 17) * k15);
        j += 16;
    }
    for (; j < cnt; j += 8) {
        int idx = j + eg;
        unsigned r = (idx < cnt) ? ep[idx] : 0u;   // r=0 -> w=0
        uint4 g = A16[(((long long)(r & 0x1FFFFu)) << 3) + d8];
        acc8(s, g, (float)(r >> 17) * k15);
    }
    #pragma unroll
    for (int k = 0; k < 8; ++k) {
        s[k] += __shfl_xor(s[k], 8, 64);
        s[k] += __shfl_xor(s[k], 16, 64);
        s[k] += __shfl_xor(s[k], 32, 64);
    }
    if (eg == 0) {
        float4* C4 = (float4*)acc;
        long long o = ((long long)node << 4) + d8 * 2;
        float4 c0 = C4[o], c1 = C4[o + 1];
        c0.x += s[0]; c0.y += s[1]; c0.z += s[2]; c0.w += s[3];
        c1.x += s[4]; c1.y += s[5]; c1.z += s[6]; c1.w += s[7];
        C4[o] = c0; C4[o + 1] = c1;
        if (writeB) {
            uint4 h;
            h.x = bf16pair(s[0], s[1]);
            h.y = bf16pair(s[2], s[3]);
            h.z = bf16pair(s[4], s[5]);
            h.w = bf16pair(s[6], s[7]);
            B16[(((long long)node) << 3) + d8] = h;
        }
    }
}

// one wave per batch element: dot(acc[u], acc[NUM_USERS+i]) / 16
__global__ void dot_kernel(const float* __restrict__ acc,
                           const int* __restrict__ users,
                           const int* __restrict__ items,
                           float* __restrict__ out) {
    int t = blockIdx.x * blockDim.x + threadIdx.x;
    int b = t >> 6;
    int d = t & 63;
    if (b >= BATCH) return;
    int u  = users[b];
    int it = items[b] + NUM_USERS;
    float p = acc[(long long)u * EMB_DIM + d] * acc[(long long)it * EMB_DIM + d];
    #pragma unroll
    for (int off = 32; off >= 1; off >>= 1)
        p += __shfl_down(p, off, 64);
    if (d == 0) out[b] = p * 0.0625f;
}

extern "C" void kernel_launch(void* const* d_in, const int* in_sizes, int n_in,
                              void* d_out, int out_size, void* d_ws, size_t ws_size,
                              hipStream_t stream) {
    const float* user_emb = (const float*)d_in[0];
    const float* item_emb = (const float*)d_in[1];
    const float* edge_val = (const float*)d_in[2];
    const int*   edge_src = (const int*)d_in[3];
    const int*   edge_dst = (const int*)d_in[4];
    const int*   users    = (const int*)d_in[5];
    const int*   items    = (const int*)d_in[6];
    float* out = (float*)d_out;

    const size_t emb16Bytes = (size_t)N_NODES * EMB_DIM * 2;             // 12.8 MB
    const size_t embBytes   = (size_t)N_NODES * EMB_DIM * sizeof(float); // 25.6 MB
    const size_t sortBytes  = (size_t)NBUCK_USED * CAP * sizeof(unsigned); // 14.4 MB
    const size_t tmpBytes   = (size_t)NBUCK_USED * CAP * sizeof(ull);    // 28.8 MB
    const size_t nodeBytes  = (size_t)N_NODES * sizeof(int);             // 400 KB

    char* w = (char*)d_ws;
    unsigned* bufA16       = (unsigned*)(w); w += emb16Bytes;
    unsigned* bufB16       = (unsigned*)(w); w += emb16Bytes;
    float*    acc          = (float*)(w);    w += embBytes;
    unsigned* sorted       = (unsigned*)(w); w += sortBytes;
    ull*      tmp          = (ull*)(w);      w += tmpBytes;
    int*      deg          = (int*)(w);      w += nodeBytes;
    int*      rowStart     = (int*)(w);      w += nodeBytes;
    int*      bucketCursor = (int*)(w);      w += NBUCK * sizeof(int);

    const int vecTotal   = N_NODES * (EMB_DIM / 4);
    const int initBlocks = (vecTotal + 255) / 256;
    const int tileBlocks = (NNZ + TILE_EDGES - 1) / TILE_EDGES;   // 391

    init_emb_kernel<<<initBlocks, 256, 0, stream>>>(user_emb, item_emb,
                                                    bufA16, acc, bucketCursor);

    partA_kernel<<<tileBlocks, 1024, 0, stream>>>(edge_val, edge_src, edge_dst,
                                                  bucketCursor, tmp);
    partB_kernel<<<NBUCK_USED, 1024, 0, stream>>>(tmp, bucketCursor,
                                                  rowStart, deg, sorted);

    const int pullBlocks = (N_NODES * 64 + 255) / 256;
    for (int layer = 0; layer < N_LAYERS; ++layer) {
        pull_kernel<<<pullBlocks, 256, 0, stream>>>((const uint4*)bufA16, (uint4*)bufB16,
                                                    acc, sorted, rowStart, deg,
                                                    layer < N_LAYERS - 1 ? 1 : 0);
        unsigned* tswap = bufA16; bufA16 = bufB16; bufB16 = tswap;
    }

    const int dotBlocks = (BATCH * 64 + 255) / 256;
    dot_kernel<<<dotBlocks, 256, 0, stream>>>(acc, users, items, out);
}

// Round 13
// 307.937 us; speedup vs baseline: 13.7599x; 1.0871x over previous
//
#include <hip/hip_runtime.h>

#define NUM_USERS 50000
#define NUM_ITEMS 50000
#define N_NODES   100000
#define NNZ       3200000
#define EMB_DIM   64
#define N_LAYERS  3
#define BATCH     16384

#define NBUCK 512
#define ABITS 8                  // bucket = dst >> 8 (256 nodes/bucket, 391 used)
#define NODES_PER_BUCK 256
#define TILE_EDGES 8192
#define NBUCK_USED ((N_NODES + NODES_PER_BUCK - 1) / NODES_PER_BUCK)   // 391
#define CAP 9216                 // padded bucket capacity (mean 8192, +11 sigma)
#define BM_WORDS ((N_NODES + 31) / 32)   // 3125

typedef unsigned long long ull;

// ---- bf16 helpers (RNE) ----
__device__ inline unsigned bf16pair(float a, float b) {
    unsigned ua = __float_as_uint(a), ub = __float_as_uint(b);
    unsigned r0 = (ua + 0x7fffu + ((ua >> 16) & 1u)) >> 16;
    unsigned r1 = (ub + 0x7fffu + ((ub >> 16) & 1u)) >> 16;
    return r0 | (r1 << 16);
}

// accumulate 8 bf16 dims (one uint4) * w into s[0..7]
__device__ inline void acc8(float* s, uint4 g, float w) {
    s[0] = fmaf(w, __uint_as_float(g.x << 16),        s[0]);
    s[1] = fmaf(w, __uint_as_float(g.x & 0xffff0000u), s[1]);
    s[2] = fmaf(w, __uint_as_float(g.y << 16),        s[2]);
    s[3] = fmaf(w, __uint_as_float(g.y & 0xffff0000u), s[3]);
    s[4] = fmaf(w, __uint_as_float(g.z << 16),        s[4]);
    s[5] = fmaf(w, __uint_as_float(g.z & 0xffff0000u), s[5]);
    s[6] = fmaf(w, __uint_as_float(g.w << 16),        s[6]);
    s[7] = fmaf(w, __uint_as_float(g.w & 0xffff0000u), s[7]);
}

// init: acc(fp32) = concat(ue, ie); bufA16(bf16) = same.
// Block 0 inits bucket cursors to padded region bases AND zeroes the node bitmap.
__global__ void init_emb_kernel(const float* __restrict__ ue,
                                const float* __restrict__ ie,
                                unsigned* __restrict__ bufA16,
                                float* __restrict__ acc,
                                int* __restrict__ bucketCursor,
                                unsigned* __restrict__ bitmap) {
    int idx = blockIdx.x * blockDim.x + threadIdx.x;   // per float4 (4 dims)
    if (blockIdx.x == 0) {
        if (threadIdx.x < 256) {
            bucketCursor[threadIdx.x]       = threadIdx.x * CAP;
            bucketCursor[threadIdx.x + 256] = (threadIdx.x + 256) * CAP;
        }
        for (int i = threadIdx.x; i < BM_WORDS; i += 256) bitmap[i] = 0;
    }
    const int total = N_NODES * (EMB_DIM / 4);
    if (idx >= total) return;
    const int uoff = NUM_USERS * (EMB_DIM / 4);
    float4 v;
    if (idx < uoff) v = ((const float4*)ue)[idx];
    else            v = ((const float4*)ie)[idx - uoff];
    ((float4*)acc)[idx] = v;
    uint2 h;
    h.x = bf16pair(v.x, v.y);
    h.y = bf16pair(v.z, v.w);
    ((uint2*)bufA16)[idx] = h;
}

// mark batch-needed nodes (users + offset items)
__global__ void flag_kernel(const int* __restrict__ users,
                            const int* __restrict__ items,
                            unsigned* __restrict__ bitmap) {
    int t = blockIdx.x * blockDim.x + threadIdx.x;
    if (t < BATCH) {
        int n = users[t];
        atomicOr(&bitmap[n >> 5], 1u << (n & 31));
    } else if (t < 2 * BATCH) {
        int n = NUM_USERS + items[t - BATCH];
        atomicOr(&bitmap[n >> 5], 1u << (n & 31));
    }
}

// partition edges into padded dst-bucket regions. 1024 threads, 8 edges/thread.
// rec: src(17) | dstLocal(8)<<17 | fix15(val)<<25
__global__ void partA_kernel(const float* __restrict__ ev,
                             const int*  __restrict__ es,
                             const int*  __restrict__ ed,
                             int* __restrict__ bucketCursor,
                             ull* __restrict__ tmp) {
    __shared__ int hist[NBUCK];
    __shared__ int base[NBUCK];
    __shared__ int cnt2[NBUCK];
    int tid = threadIdx.x;            // 1024
    int e0 = blockIdx.x * TILE_EDGES;

    int      mySrc[8], myDst[8];
    unsigned myQ[8];

    for (int i = tid; i < NBUCK; i += 1024) hist[i] = 0;
    __syncthreads();

    #pragma unroll
    for (int k = 0; k < 8; ++k) {
        int e = e0 + k * 1024 + tid;
        if (e < NNZ) {
            mySrc[k] = es[e];
            myDst[k] = ed[e];
            myQ[k]   = (unsigned)fminf(ev[e] * 32768.f + 0.5f, 32767.f);
            atomicAdd(&hist[((unsigned)myDst[k]) >> ABITS], 1);
        } else {
            myDst[k] = -1;
        }
    }
    __syncthreads();

    for (int i = tid; i < NBUCK; i += 1024) {
        int c = hist[i];
        base[i] = c ? atomicAdd(&bucketCursor[i], c) : 0;
        cnt2[i] = 0;
    }
    __syncthreads();

    #pragma unroll
    for (int k = 0; k < 8; ++k) {
        int dst = myDst[k];
        if (dst < 0) continue;
        int b = ((unsigned)dst) >> ABITS;
        int pos = base[b] + atomicAdd(&cnt2[b], 1);
        if (pos < (b + 1) * CAP) {   // statistically unreachable overflow guard
            ull rec = (ull)(unsigned)(mySrc[k] | ((dst & (NODES_PER_BUCK - 1)) << 17))
                    | ((ull)myQ[k] << 25);
            tmp[pos] = rec;
        }
    }
}

// partB: per bucket — single-pass: register-cache records (<=9/thread), node degrees
// + rowStart via LDS scan, scatter from registers to padded-CSR positions.
// sorted rec (u32): src(17) | fix15(val)<<17
__global__ void partB_kernel(const ull* __restrict__ tmp,
                             const int* __restrict__ bucketCursor,
                             int* __restrict__ rowStart,
                             int* __restrict__ deg,
                             unsigned* __restrict__ sorted) {
    __shared__ int cnt[NODES_PER_BUCK];
    __shared__ int sc[NODES_PER_BUCK];
    __shared__ int cur[NODES_PER_BUCK];
    int b = blockIdx.x;
    int tid = threadIdx.x;           // 1024
    int nodeLo = b << ABITS;
    int startE = b * CAP;
    int endE   = bucketCursor[b];    // base + edges in bucket

    if (tid < NODES_PER_BUCK) cnt[tid] = 0;
    __syncthreads();

    ull myRec[9];
    int nRec = 0;
    #pragma unroll
    for (int k = 0; k < 9; ++k) {
        int i = startE + k * 1024 + tid;
        if (i < endE) {
            myRec[k] = tmp[i];
            nRec = k + 1;
            atomicAdd(&cnt[(int)((myRec[k] >> 17) & (NODES_PER_BUCK - 1))], 1);
        }
    }
    __syncthreads();

    if (tid < NODES_PER_BUCK) sc[tid] = cnt[tid];
    __syncthreads();
    for (int o = 1; o < NODES_PER_BUCK; o <<= 1) {
        int add = 0;
        if (tid < NODES_PER_BUCK && tid >= o) add = sc[tid - o];
        __syncthreads();
        if (tid < NODES_PER_BUCK) sc[tid] += add;
        __syncthreads();
    }
    if (tid < NODES_PER_BUCK) {
        int node = nodeLo + tid;
        int rs = startE + sc[tid] - cnt[tid];
        cur[tid] = rs;
        if (node < N_NODES) {
            rowStart[node] = rs;          // index into padded sorted array
            deg[node] = cnt[tid];
        }
    }
    __syncthreads();

    for (int k = 0; k < nRec; ++k) {
        ull rec = myRec[k];
        int dl = (int)((rec >> 17) & (NODES_PER_BUCK - 1));
        unsigned o = (unsigned)(rec & 0x1FFFFULL) | ((unsigned)((rec >> 25) & 0x7FFF) << 17);
        int pos = atomicAdd(&cur[dl], 1);
        sorted[pos] = o;
    }
}

// ---- pull: one wave per dst node; lane = (eg=lane>>3 edge subgroup, d8=lane&7 dim octet).
// u32 edge records; uint4 bf16 gathers; 32 edges in flight. Optional bitmap gate
// (last layer: only batch-needed nodes are computed).
__global__ void pull_kernel(const uint4* __restrict__ A16,
                            uint4* __restrict__ B16,
                            float* __restrict__ acc,
                            const unsigned* __restrict__ sorted,
                            const int* __restrict__ rowStart,
                            const int* __restrict__ deg,
                            const unsigned* __restrict__ bitmap,
                            int writeB, int gate) {
    int t = blockIdx.x * blockDim.x + threadIdx.x;
    int node = t >> 6;
    if (node >= N_NODES) return;
    if (gate && !((bitmap[node >> 5] >> (node & 31)) & 1u)) return;  // wave-uniform
    int lane = t & 63;
    int eg = lane >> 3;      // 0..7
    int d8 = lane & 7;       // dim octet (16 B)
    int start = rowStart[node];
    int cnt   = deg[node];   // wave-uniform
    const unsigned* ep = sorted + start;
    const float k15 = 1.f / 32768.f;

    float s[8] = {0.f,0.f,0.f,0.f,0.f,0.f,0.f,0.f};
    int j = 0;
    while (j + 32 <= cnt) {
        unsigned r0 = ep[j + eg], r1 = ep[j + 8 + eg];
        unsigned r2 = ep[j + 16 + eg], r3 = ep[j + 24 + eg];
        uint4 g0 = A16[(((long long)(r0 & 0x1FFFFu)) << 3) + d8];
        uint4 g1 = A16[(((long long)(r1 & 0x1FFFFu)) << 3) + d8];
        uint4 g2 = A16[(((long long)(r2 & 0x1FFFFu)) << 3) + d8];
        uint4 g3 = A16[(((long long)(r3 & 0x1FFFFu)) << 3) + d8];
        acc8(s, g0, (float)(r0 >> 17) * k15);
        acc8(s, g1, (float)(r1 >> 17) * k15);
        acc8(s, g2, (float)(r2 >> 17) * k15);
        acc8(s, g3, (float)(r3 >> 17) * k15);
        j += 32;
    }
    while (j + 16 <= cnt) {
        unsigned r0 = ep[j + eg], r1 = ep[j + 8 + eg];
        uint4 g0 = A16[(((long long)(r0 & 0x1FFFFu)) << 3) + d8];
        uint4 g1 = A16[(((long long)(r1 & 0x1FFFFu)) << 3) + d8];
        acc8(s, g0, (float)(r0 >> 17) * k15);
        acc8(s, g1, (float)(r1 >> 17) * k15);
        j += 16;
    }
    for (; j < cnt; j += 8) {
        int idx = j + eg;
        unsigned r = (idx < cnt) ? ep[idx] : 0u;   // r=0 -> w=0
        uint4 g = A16[(((long long)(r & 0x1FFFFu)) << 3) + d8];
        acc8(s, g, (float)(r >> 17) * k15);
    }
    #pragma unroll
    for (int k = 0; k < 8; ++k) {
        s[k] += __shfl_xor(s[k], 8, 64);
        s[k] += __shfl_xor(s[k], 16, 64);
        s[k] += __shfl_xor(s[k], 32, 64);
    }
    if (eg == 0) {
        float4* C4 = (float4*)acc;
        long long o = ((long long)node << 4) + d8 * 2;
        float4 c0 = C4[o], c1 = C4[o + 1];
        c0.x += s[0]; c0.y += s[1]; c0.z += s[2]; c0.w += s[3];
        c1.x += s[4]; c1.y += s[5]; c1.z += s[6]; c1.w += s[7];
        C4[o] = c0; C4[o + 1] = c1;
        if (writeB) {
            uint4 h;
            h.x = bf16pair(s[0], s[1]);
            h.y = bf16pair(s[2], s[3]);
            h.z = bf16pair(s[4], s[5]);
            h.w = bf16pair(s[6], s[7]);
            B16[(((long long)node) << 3) + d8] = h;
        }
    }
}

// one wave per batch element: dot(acc[u], acc[NUM_USERS+i]) / 16
__global__ void dot_kernel(const float* __restrict__ acc,
                           const int* __restrict__ users,
                           const int* __restrict__ items,
                           float* __restrict__ out) {
    int t = blockIdx.x * blockDim.x + threadIdx.x;
    int b = t >> 6;
    int d = t & 63;
    if (b >= BATCH) return;
    int u  = users[b];
    int it = items[b] + NUM_USERS;
    float p = acc[(long long)u * EMB_DIM + d] * acc[(long long)it * EMB_DIM + d];
    #pragma unroll
    for (int off = 32; off >= 1; off >>= 1)
        p += __shfl_down(p, off, 64);
    if (d == 0) out[b] = p * 0.0625f;
}

extern "C" void kernel_launch(void* const* d_in, const int* in_sizes, int n_in,
                              void* d_out, int out_size, void* d_ws, size_t ws_size,
                              hipStream_t stream) {
    const float* user_emb = (const float*)d_in[0];
    const float* item_emb = (const float*)d_in[1];
    const float* edge_val = (const float*)d_in[2];
    const int*   edge_src = (const int*)d_in[3];
    const int*   edge_dst = (const int*)d_in[4];
    const int*   users    = (const int*)d_in[5];
    const int*   items    = (const int*)d_in[6];
    float* out = (float*)d_out;

    const size_t emb16Bytes = (size_t)N_NODES * EMB_DIM * 2;               // 12.8 MB
    const size_t embBytes   = (size_t)N_NODES * EMB_DIM * sizeof(float);   // 25.6 MB
    const size_t sortBytes  = (size_t)NBUCK_USED * CAP * sizeof(unsigned); // 14.4 MB
    const size_t tmpBytes   = (size_t)NBUCK_USED * CAP * sizeof(ull);      // 28.8 MB
    const size_t nodeBytes  = (size_t)N_NODES * sizeof(int);               // 400 KB

    char* w = (char*)d_ws;
    unsigned* bufA16       = (unsigned*)(w); w += emb16Bytes;
    unsigned* bufB16       = (unsigned*)(w); w += emb16Bytes;
    float*    acc          = (float*)(w);    w += embBytes;
    unsigned* sorted       = (unsigned*)(w); w += sortBytes;
    ull*      tmp          = (ull*)(w);      w += tmpBytes;
    int*      deg          = (int*)(w);      w += nodeBytes;
    int*      rowStart     = (int*)(w);      w += nodeBytes;
    int*      bucketCursor = (int*)(w);      w += NBUCK * sizeof(int);
    unsigned* bitmap       = (unsigned*)(w); w += BM_WORDS * sizeof(unsigned);

    const int vecTotal   = N_NODES * (EMB_DIM / 4);
    const int initBlocks = (vecTotal + 255) / 256;
    const int tileBlocks = (NNZ + TILE_EDGES - 1) / TILE_EDGES;   // 391

    init_emb_kernel<<<initBlocks, 256, 0, stream>>>(user_emb, item_emb,
                                                    bufA16, acc, bucketCursor, bitmap);
    flag_kernel<<<(2 * BATCH + 255) / 256, 256, 0, stream>>>(users, items, bitmap);

    partA_kernel<<<tileBlocks, 1024, 0, stream>>>(edge_val, edge_src, edge_dst,
                                                  bucketCursor, tmp);
    partB_kernel<<<NBUCK_USED, 1024, 0, stream>>>(tmp, bucketCursor,
                                                  rowStart, deg, sorted);

    const int pullBlocks = (N_NODES * 64 + 255) / 256;
    for (int layer = 0; layer < N_LAYERS; ++layer) {
        int last = (layer == N_LAYERS - 1);
        pull_kernel<<<pullBlocks, 256, 0, stream>>>((const uint4*)bufA16, (uint4*)bufB16,
                                                    acc, sorted, rowStart, deg, bitmap,
                                                    last ? 0 : 1, last ? 1 : 0);
        unsigned* tswap = bufA16; bufA16 = bufB16; bufB16 = tswap;
    }

    const int dotBlocks = (BATCH * 64 + 255) / 256;
    dot_kernel<<<dotBlocks, 256, 0, stream>>>(acc, users, items, out);
}

// Round 14
// 287.594 us; speedup vs baseline: 14.7332x; 1.0707x over previous
//
#include <hip/hip_runtime.h>

#define NUM_USERS 50000
#define NUM_ITEMS 50000
#define N_NODES   100000
#define NNZ       3200000
#define EMB_DIM   64
#define N_LAYERS  3
#define BATCH     16384

#define NBUCK 512
#define ABITS 8                  // bucket = dst >> 8 (256 nodes/bucket, 391 used)
#define NODES_PER_BUCK 256
#define TILE_EDGES 8192
#define NBUCK_USED ((N_NODES + NODES_PER_BUCK - 1) / NODES_PER_BUCK)   // 391
#define CAP 9216                 // padded bucket capacity (mean 8192, +11 sigma)
#define BM_WORDS ((N_NODES + 31) / 32)   // 3125

typedef unsigned long long ull;

// ---- bf16 helpers (RNE) ----
__device__ inline unsigned bf16pair(float a, float b) {
    unsigned ua = __float_as_uint(a), ub = __float_as_uint(b);
    unsigned r0 = (ua + 0x7fffu + ((ua >> 16) & 1u)) >> 16;
    unsigned r1 = (ub + 0x7fffu + ((ub >> 16) & 1u)) >> 16;
    return r0 | (r1 << 16);
}
__device__ inline float blo(unsigned u) { return __uint_as_float(u << 16); }
__device__ inline float bhi(unsigned u) { return __uint_as_float(u & 0xffff0000u); }

// accumulate 8 bf16 dims (one uint4) * w into s[0..7]
__device__ inline void acc8(float* s, uint4 g, float w) {
    s[0] = fmaf(w, blo(g.x), s[0]); s[1] = fmaf(w, bhi(g.x), s[1]);
    s[2] = fmaf(w, blo(g.y), s[2]); s[3] = fmaf(w, bhi(g.y), s[3]);
    s[4] = fmaf(w, blo(g.z), s[4]); s[5] = fmaf(w, bhi(g.z), s[5]);
    s[6] = fmaf(w, blo(g.w), s[6]); s[7] = fmaf(w, bhi(g.w), s[7]);
}

// init: E0(bf16) = concat(ue, ie). Block 0 inits bucket cursors + zeroes bitmap.
__global__ void init_emb_kernel(const float* __restrict__ ue,
                                const float* __restrict__ ie,
                                unsigned* __restrict__ E0,
                                int* __restrict__ bucketCursor,
                                unsigned* __restrict__ bitmap) {
    int idx = blockIdx.x * blockDim.x + threadIdx.x;   // per float4 (4 dims)
    if (blockIdx.x == 0) {
        if (threadIdx.x < 256) {
            bucketCursor[threadIdx.x]       = threadIdx.x * CAP;
            bucketCursor[threadIdx.x + 256] = (threadIdx.x + 256) * CAP;
        }
        for (int i = threadIdx.x; i < BM_WORDS; i += 256) bitmap[i] = 0;
    }
    const int total = N_NODES * (EMB_DIM / 4);
    if (idx >= total) return;
    const int uoff = NUM_USERS * (EMB_DIM / 4);
    float4 v;
    if (idx < uoff) v = ((const float4*)ue)[idx];
    else            v = ((const float4*)ie)[idx - uoff];
    uint2 h;
    h.x = bf16pair(v.x, v.y);
    h.y = bf16pair(v.z, v.w);
    ((uint2*)E0)[idx] = h;
}

// mark batch-needed nodes (users + offset items)
__global__ void flag_kernel(const int* __restrict__ users,
                            const int* __restrict__ items,
                            unsigned* __restrict__ bitmap) {
    int t = blockIdx.x * blockDim.x + threadIdx.x;
    if (t < BATCH) {
        int n = users[t];
        atomicOr(&bitmap[n >> 5], 1u << (n & 31));
    } else if (t < 2 * BATCH) {
        int n = NUM_USERS + items[t - BATCH];
        atomicOr(&bitmap[n >> 5], 1u << (n & 31));
    }
}

// partition edges into padded dst-bucket regions. 1024 threads, 8 edges/thread.
// rec: src(17) | dstLocal(8)<<17 | fix15(val)<<25
__global__ void partA_kernel(const float* __restrict__ ev,
                             const int*  __restrict__ es,
                             const int*  __restrict__ ed,
                             int* __restrict__ bucketCursor,
                             ull* __restrict__ tmp) {
    __shared__ int hist[NBUCK];
    __shared__ int base[NBUCK];
    __shared__ int cnt2[NBUCK];
    int tid = threadIdx.x;            // 1024
    int e0 = blockIdx.x * TILE_EDGES;

    int      mySrc[8], myDst[8];
    unsigned myQ[8];

    for (int i = tid; i < NBUCK; i += 1024) hist[i] = 0;
    __syncthreads();

    #pragma unroll
    for (int k = 0; k < 8; ++k) {
        int e = e0 + k * 1024 + tid;
        if (e < NNZ) {
            mySrc[k] = es[e];
            myDst[k] = ed[e];
            myQ[k]   = (unsigned)fminf(ev[e] * 32768.f + 0.5f, 32767.f);
            atomicAdd(&hist[((unsigned)myDst[k]) >> ABITS], 1);
        } else {
            myDst[k] = -1;
        }
    }
    __syncthreads();

    for (int i = tid; i < NBUCK; i += 1024) {
        int c = hist[i];
        base[i] = c ? atomicAdd(&bucketCursor[i], c) : 0;
        cnt2[i] = 0;
    }
    __syncthreads();

    #pragma unroll
    for (int k = 0; k < 8; ++k) {
        int dst = myDst[k];
        if (dst < 0) continue;
        int b = ((unsigned)dst) >> ABITS;
        int pos = base[b] + atomicAdd(&cnt2[b], 1);
        if (pos < (b + 1) * CAP) {   // statistically unreachable overflow guard
            ull rec = (ull)(unsigned)(mySrc[k] | ((dst & (NODES_PER_BUCK - 1)) << 17))
                    | ((ull)myQ[k] << 25);
            tmp[pos] = rec;
        }
    }
}

// partB: per bucket — single-pass: register-cache records (<=9/thread), node degrees
// + rowStart via LDS scan, scatter from registers to padded-CSR positions.
// sorted rec (u32): src(17) | fix15(val)<<17
__global__ void partB_kernel(const ull* __restrict__ tmp,
                             const int* __restrict__ bucketCursor,
                             int* __restrict__ rowStart,
                             int* __restrict__ deg,
                             unsigned* __restrict__ sorted) {
    __shared__ int cnt[NODES_PER_BUCK];
    __shared__ int sc[NODES_PER_BUCK];
    __shared__ int cur[NODES_PER_BUCK];
    int b = blockIdx.x;
    int tid = threadIdx.x;           // 1024
    int nodeLo = b << ABITS;
    int startE = b * CAP;
    int endE   = bucketCursor[b];    // base + edges in bucket

    if (tid < NODES_PER_BUCK) cnt[tid] = 0;
    __syncthreads();

    ull myRec[9];
    int nRec = 0;
    #pragma unroll
    for (int k = 0; k < 9; ++k) {
        int i = startE + k * 1024 + tid;
        if (i < endE) {
            myRec[k] = tmp[i];
            nRec = k + 1;
            atomicAdd(&cnt[(int)((myRec[k] >> 17) & (NODES_PER_BUCK - 1))], 1);
        }
    }
    __syncthreads();

    if (tid < NODES_PER_BUCK) sc[tid] = cnt[tid];
    __syncthreads();
    for (int o = 1; o < NODES_PER_BUCK; o <<= 1) {
        int add = 0;
        if (tid < NODES_PER_BUCK && tid >= o) add = sc[tid - o];
        __syncthreads();
        if (tid < NODES_PER_BUCK) sc[tid] += add;
        __syncthreads();
    }
    if (tid < NODES_PER_BUCK) {
        int node = nodeLo + tid;
        int rs = startE + sc[tid] - cnt[tid];
        cur[tid] = rs;
        if (node < N_NODES) {
            rowStart[node] = rs;          // index into padded sorted array
            deg[node] = cnt[tid];
        }
    }
    __syncthreads();

    for (int k = 0; k < nRec; ++k) {
        ull rec = myRec[k];
        int dl = (int)((rec >> 17) & (NODES_PER_BUCK - 1));
        unsigned o = (unsigned)(rec & 0x1FFFFULL) | ((unsigned)((rec >> 25) & 0x7FFF) << 17);
        int pos = atomicAdd(&cur[dl], 1);
        sorted[pos] = o;
    }
}

// ---- pull: one wave per dst node; lane = (eg=lane>>3, d8=lane&7).
// Reads bf16 A16, writes bf16 B16 only (no fp32 acc). Optional bitmap gate.
__global__ void pull_kernel(const uint4* __restrict__ A16,
                            uint4* __restrict__ B16,
                            const unsigned* __restrict__ sorted,
                            const int* __restrict__ rowStart,
                            const int* __restrict__ deg,
                            const unsigned* __restrict__ bitmap,
                            int gate) {
    int t = blockIdx.x * blockDim.x + threadIdx.x;
    int node = t >> 6;
    if (node >= N_NODES) return;
    if (gate && !((bitmap[node >> 5] >> (node & 31)) & 1u)) return;  // wave-uniform
    int lane = t & 63;
    int eg = lane >> 3;      // 0..7
    int d8 = lane & 7;       // dim octet (16 B)
    int start = rowStart[node];
    int cnt   = deg[node];   // wave-uniform
    const unsigned* ep = sorted + start;
    const float k15 = 1.f / 32768.f;

    float s[8] = {0.f,0.f,0.f,0.f,0.f,0.f,0.f,0.f};
    int j = 0;
    while (j + 32 <= cnt) {
        unsigned r0 = ep[j + eg], r1 = ep[j + 8 + eg];
        unsigned r2 = ep[j + 16 + eg], r3 = ep[j + 24 + eg];
        uint4 g0 = A16[(((long long)(r0 & 0x1FFFFu)) << 3) + d8];
        uint4 g1 = A16[(((long long)(r1 & 0x1FFFFu)) << 3) + d8];
        uint4 g2 = A16[(((long long)(r2 & 0x1FFFFu)) << 3) + d8];
        uint4 g3 = A16[(((long long)(r3 & 0x1FFFFu)) << 3) + d8];
        acc8(s, g0, (float)(r0 >> 17) * k15);
        acc8(s, g1, (float)(r1 >> 17) * k15);
        acc8(s, g2, (float)(r2 >> 17) * k15);
        acc8(s, g3, (float)(r3 >> 17) * k15);
        j += 32;
    }
    while (j + 16 <= cnt) {
        unsigned r0 = ep[j + eg], r1 = ep[j + 8 + eg];
        uint4 g0 = A16[(((long long)(r0 & 0x1FFFFu)) << 3) + d8];
        uint4 g1 = A16[(((long long)(r1 & 0x1FFFFu)) << 3) + d8];
        acc8(s, g0, (float)(r0 >> 17) * k15);
        acc8(s, g1, (float)(r1 >> 17) * k15);
        j += 16;
    }
    for (; j < cnt; j += 8) {
        int idx = j + eg;
        unsigned r = (idx < cnt) ? ep[idx] : 0u;   // r=0 -> w=0
        uint4 g = A16[(((long long)(r & 0x1FFFFu)) << 3) + d8];
        acc8(s, g, (float)(r >> 17) * k15);
    }
    #pragma unroll
    for (int k = 0; k < 8; ++k) {
        s[k] += __shfl_xor(s[k], 8, 64);
        s[k] += __shfl_xor(s[k], 16, 64);
        s[k] += __shfl_xor(s[k], 32, 64);
    }
    if (eg == 0) {
        uint4 h;
        h.x = bf16pair(s[0], s[1]);
        h.y = bf16pair(s[2], s[3]);
        h.z = bf16pair(s[4], s[5]);
        h.w = bf16pair(s[6], s[7]);
        B16[(((long long)node) << 3) + d8] = h;
    }
}

// dot: half-wave (32 lanes) per batch element; lane covers 2 dims (one uint).
// gamma = dot( sum_l U_l , sum_l I_l ) / 16, layers read from E0,B1,B2,B3.
__global__ void dot_kernel(const unsigned* __restrict__ E0,
                           const unsigned* __restrict__ B1,
                           const unsigned* __restrict__ B2,
                           const unsigned* __restrict__ B3,
                           const int* __restrict__ users,
                           const int* __restrict__ items,
                           float* __restrict__ out) {
    int t = blockIdx.x * blockDim.x + threadIdx.x;
    int b = t >> 5;
    int lane = t & 31;
    if (b >= BATCH) return;
    long long uo = ((long long)users[b] << 5) + lane;
    long long io = ((long long)(items[b] + NUM_USERS) << 5) + lane;
    unsigned a0 = E0[uo], a1 = B1[uo], a2 = B2[uo], a3 = B3[uo];
    unsigned c0 = E0[io], c1 = B1[io], c2 = B2[io], c3 = B3[io];
    float ux = (blo(a0) + blo(a1)) + (blo(a2) + blo(a3));
    float uy = (bhi(a0) + bhi(a1)) + (bhi(a2) + bhi(a3));
    float ix = (blo(c0) + blo(c1)) + (blo(c2) + blo(c3));
    float iy = (bhi(c0) + bhi(c1)) + (bhi(c2) + bhi(c3));
    float p = ux * ix + uy * iy;
    #pragma unroll
    for (int off = 16; off >= 1; off >>= 1)
        p += __shfl_xor(p, off, 64);   // stays within the aligned 32-group
    if (lane == 0) out[b] = p * 0.0625f;
}

extern "C" void kernel_launch(void* const* d_in, const int* in_sizes, int n_in,
                              void* d_out, int out_size, void* d_ws, size_t ws_size,
                              hipStream_t stream) {
    const float* user_emb = (const float*)d_in[0];
    const float* item_emb = (const float*)d_in[1];
    const float* edge_val = (const float*)d_in[2];
    const int*   edge_src = (const int*)d_in[3];
    const int*   edge_dst = (const int*)d_in[4];
    const int*   users    = (const int*)d_in[5];
    const int*   items    = (const int*)d_in[6];
    float* out = (float*)d_out;

    const size_t emb16Bytes = (size_t)N_NODES * EMB_DIM * 2;               // 12.8 MB
    const size_t sortBytes  = (size_t)NBUCK_USED * CAP * sizeof(unsigned); // 14.4 MB
    const size_t tmpBytes   = (size_t)NBUCK_USED * CAP * sizeof(ull);      // 28.8 MB
    const size_t nodeBytes  = (size_t)N_NODES * sizeof(int);               // 400 KB

    char* w = (char*)d_ws;
    unsigned* E0           = (unsigned*)(w); w += emb16Bytes;
    unsigned* B1           = (unsigned*)(w); w += emb16Bytes;
    unsigned* B2           = (unsigned*)(w); w += emb16Bytes;
    unsigned* B3           = (unsigned*)(w); w += emb16Bytes;
    unsigned* sorted       = (unsigned*)(w); w += sortBytes;
    ull*      tmp          = (ull*)(w);      w += tmpBytes;
    int*      deg          = (int*)(w);      w += nodeBytes;
    int*      rowStart     = (int*)(w);      w += nodeBytes;
    int*      bucketCursor = (int*)(w);      w += NBUCK * sizeof(int);
    unsigned* bitmap       = (unsigned*)(w); w += BM_WORDS * sizeof(unsigned);

    const int vecTotal   = N_NODES * (EMB_DIM / 4);
    const int initBlocks = (vecTotal + 255) / 256;
    const int tileBlocks = (NNZ + TILE_EDGES - 1) / TILE_EDGES;   // 391

    init_emb_kernel<<<initBlocks, 256, 0, stream>>>(user_emb, item_emb,
                                                    E0, bucketCursor, bitmap);
    flag_kernel<<<(2 * BATCH + 255) / 256, 256, 0, stream>>>(users, items, bitmap);

    partA_kernel<<<tileBlocks, 1024, 0, stream>>>(edge_val, edge_src, edge_dst,
                                                  bucketCursor, tmp);
    partB_kernel<<<NBUCK_USED, 1024, 0, stream>>>(tmp, bucketCursor,
                                                  rowStart, deg, sorted);

    const int pullBlocks = (N_NODES * 64 + 255) / 256;
    pull_kernel<<<pullBlocks, 256, 0, stream>>>((const uint4*)E0, (uint4*)B1,
                                                sorted, rowStart, deg, bitmap, 0);
    pull_kernel<<<pullBlocks, 256, 0, stream>>>((const uint4*)B1, (uint4*)B2,
                                                sorted, rowStart, deg, bitmap, 0);
    pull_kernel<<<pullBlocks, 256, 0, stream>>>((const uint4*)B2, (uint4*)B3,
                                                sorted, rowStart, deg, bitmap, 1);

    const int dotBlocks = (BATCH * 32 + 255) / 256;
    dot_kernel<<<dotBlocks, 256, 0, stream>>>(E0, B1, B2, B3, users, items, out);
}